// Round 5
// baseline (768.056 us; speedup 1.0000x reference)
//
#include <hip/hip_runtime.h>

// RISnetPIv2: B=128, U=16, A=1024, FEAT=4, INFO=8.
// Factored features: ll[B,U,A,8] bf16, lg[B,U,8] fp32, gl[B,A,8] bf16, gg[B,8] fp32.
// Block 256 = 4 waves; wave j owns branch j (8 out channels) -> weights hoisted
// to SGPRs, 32-50 VGPRs/thread. Ping-pong ll buffers (A,B) + pinned f3 (C):
// no in-place -> NO per-u __syncthreads (round 4's barrier convoy = 97us at
// 13% HBM). L7's f3 ll-skip is applied inside layer_out instead.
// Fallback (ws too small): 2-buffer in-place variant with per-u barrier.

#define NB 128
#define NU 16
#define NA 1024

static constexpr float PI_F = 3.14159265358979323846f;

__device__ __forceinline__ float wave_reduce_sum(float v) {
#pragma unroll
    for (int d = 1; d < 64; d <<= 1) v += __shfl_xor(v, d, 64);
    return v;
}

__device__ __forceinline__ unsigned short f2bf(float f) {  // RNE
    unsigned int u = __float_as_uint(f);
    u += 0x7fffu + ((u >> 16) & 1u);
    return (unsigned short)(u >> 16);
}
__device__ __forceinline__ unsigned int pack2(float a, float b) {
    return (unsigned int)f2bf(a) | ((unsigned int)f2bf(b) << 16);
}
__device__ __forceinline__ void load8(const unsigned short* p, float x[8]) {
    uint4 v = *reinterpret_cast<const uint4*>(p);
    x[0] = __uint_as_float(v.x << 16); x[1] = __uint_as_float(v.x & 0xffff0000u);
    x[2] = __uint_as_float(v.y << 16); x[3] = __uint_as_float(v.y & 0xffff0000u);
    x[4] = __uint_as_float(v.z << 16); x[5] = __uint_as_float(v.z & 0xffff0000u);
    x[6] = __uint_as_float(v.w << 16); x[7] = __uint_as_float(v.w & 0xffff0000u);
}
__device__ __forceinline__ void store8(unsigned short* p, const float x[8]) {
    uint4 v;
    v.x = pack2(x[0], x[1]); v.y = pack2(x[2], x[3]);
    v.z = pack2(x[4], x[5]); v.w = pack2(x[6], x[7]);
    *reinterpret_cast<uint4*>(p) = v;
}

// ---------------- Layer 1 ----------------
__global__ __launch_bounds__(256, 8) void layer_first(
    const float* __restrict__ ch, const float* __restrict__ W1,
    const float* __restrict__ b1, unsigned short* __restrict__ ll_out,
    float* __restrict__ lg_sum, unsigned short* __restrict__ gl_out,
    float* __restrict__ gg_sum)
{
    const int b = blockIdx.x;
    const int abase = blockIdx.y * 64;
    const int lane = threadIdx.x & 63;
    const int j = __builtin_amdgcn_readfirstlane((int)(threadIdx.x >> 6));
    const int a = abase + lane;

    const float* Wj = W1 + j * 32;
    const float* bj = b1 + j * 8;

    float acc[8];
#pragma unroll
    for (int i = 0; i < 8; ++i) acc[i] = 0.f;

    for (int u = 0; u < NU; ++u) {
        float x[4];
#pragma unroll
        for (int c = 0; c < 4; ++c)
            x[c] = ch[(((size_t)b * 4 + c) * NU + u) * NA + a];

        float y[8];
#pragma unroll
        for (int i = 0; i < 8; ++i) y[i] = bj[i];
#pragma unroll
        for (int c = 0; c < 4; ++c) {
            const float* wr = Wj + c * 8;
#pragma unroll
            for (int i = 0; i < 8; ++i) y[i] = fmaf(x[c], wr[i], y[i]);
        }
#pragma unroll
        for (int i = 0; i < 8; ++i) y[i] = fmaxf(y[i], 0.f);

        if (j == 0) {
            store8(ll_out + (((size_t)(b * NU + u)) * NA + a) * 8, y);
        } else if (j == 1) {
            float s[8];
#pragma unroll
            for (int i = 0; i < 8; ++i) s[i] = wave_reduce_sum(y[i]);
            if (lane == 0) {
                float* lp = lg_sum + (b * NU + u) * 8;
#pragma unroll
                for (int i = 0; i < 8; ++i) atomicAdd(lp + i, s[i]);
            }
        } else {
#pragma unroll
            for (int i = 0; i < 8; ++i) acc[i] += y[i];
        }
    }
    if (j == 2) {
        const float invU = 1.f / 16.f;
#pragma unroll
        for (int i = 0; i < 8; ++i) acc[i] *= invU;
        store8(gl_out + ((size_t)b * NA + a) * 8, acc);
    } else if (j == 3) {
#pragma unroll
        for (int i = 0; i < 8; ++i) acc[i] = wave_reduce_sum(acc[i]);
        if (lane == 0) {
            float* gp2 = gg_sum + b * 8;
#pragma unroll
            for (int i = 0; i < 8; ++i) atomicAdd(gp2 + i, acc[i]);
        }
    }
}

// -------- prep: base[b,u,32] = bias + lg·W_lg + gg·W_gg ----------
__global__ __launch_bounds__(256) void prep_base_k(
    const float* __restrict__ lg_sum, const float* __restrict__ lg_skip,
    const float* __restrict__ gg_sum, const float* __restrict__ gg_skip,
    const float* __restrict__ Wl, const float* __restrict__ bl,
    float* __restrict__ base)
{
    const int t = blockIdx.x * 256 + threadIdx.x;
    if (t >= NB * NU) return;
    const int b = t >> 4;
    const float invA = 1.f / 1024.f, invUA = 1.f / 16384.f;
    float lg[8], gg[8];
#pragma unroll
    for (int c = 0; c < 8; ++c) {
        float v = lg_sum[t * 8 + c] * invA;
        if (lg_skip) v = (v + lg_skip[t * 8 + c] * invA) * 0.5f;
        lg[c] = v;
    }
#pragma unroll
    for (int c = 0; c < 8; ++c) {
        float v = gg_sum[b * 8 + c] * invUA;
        if (gg_skip) v = (v + gg_skip[b * 8 + c] * invUA) * 0.5f;
        gg[c] = v;
    }
    float y[32];
#pragma unroll
    for (int o = 0; o < 32; ++o) y[o] = bl[o];
#pragma unroll
    for (int j = 0; j < 4; ++j)
#pragma unroll
        for (int c = 0; c < 8; ++c) {
            const float* wl = Wl + (j * 32 + 8 + c) * 8;
            const float* wg = Wl + (j * 32 + 24 + c) * 8;
#pragma unroll
            for (int oi = 0; oi < 8; ++oi) {
                y[j * 8 + oi] = fmaf(lg[c], wl[oi], y[j * 8 + oi]);
                y[j * 8 + oi] = fmaf(gg[c], wg[oi], y[j * 8 + oi]);
            }
        }
#pragma unroll
    for (int o = 0; o < 32; ++o) base[t * 32 + o] = y[o];
}

// ---------------- Layers 2..7: PING-PONG (no barrier, no aliasing) -------------
__global__ __launch_bounds__(256, 8) void layer_main_pp(
    const unsigned short* __restrict__ ll_in,
    const unsigned short* __restrict__ gl_in,
    const unsigned short* __restrict__ gl_skip,
    const float* __restrict__ base, const float* __restrict__ Wl,
    const float* __restrict__ ch, const float* __restrict__ W1,
    const float* __restrict__ b1,                 // layer 5: recompute f1 ll
    unsigned short* __restrict__ ll_out, float* __restrict__ lg_sum,
    unsigned short* __restrict__ gl_out, float* __restrict__ gg_sum)
{
    const int b = blockIdx.x;
    const int abase = blockIdx.y * 64;
    const int lane = threadIdx.x & 63;
    const int j = __builtin_amdgcn_readfirstlane((int)(threadIdx.x >> 6));
    const int a = abase + lane;

    float g[8];
    load8(gl_in + ((size_t)b * NA + a) * 8, g);
    if (gl_skip) {
        float s[8];
        load8(gl_skip + ((size_t)b * NA + a) * 8, s);
#pragma unroll
        for (int i = 0; i < 8; ++i) g[i] = (g[i] + s[i]) * 0.5f;
    }
    float cj[8];
#pragma unroll
    for (int i = 0; i < 8; ++i) cj[i] = 0.f;
#pragma unroll
    for (int c = 0; c < 8; ++c) {
        const float* wr = Wl + (j * 32 + 16 + c) * 8;   // wave-uniform
#pragma unroll
        for (int i = 0; i < 8; ++i) cj[i] = fmaf(g[c], wr[i], cj[i]);
    }

    const float* Wx = Wl + j * 256;

    float acc[8];
#pragma unroll
    for (int i = 0; i < 8; ++i) acc[i] = 0.f;

    const size_t base_off = ((size_t)(b * NU)) * NA + a;
    float x[2][8];
    load8(ll_in + base_off * 8, x[0]);          // prefetch u=0

#pragma unroll 2
    for (int u = 0; u < NU; ++u) {
        const int cur = u & 1;
        if (u + 1 < NU)                          // prefetch u+1
            load8(ll_in + (base_off + (size_t)(u + 1) * NA) * 8, x[cur ^ 1]);

        const float* bp = base + (b * NU + u) * 32 + j * 8;  // wave-uniform
        float y[8];
#pragma unroll
        for (int i = 0; i < 8; ++i) y[i] = cj[i] + bp[i];
#pragma unroll
        for (int c = 0; c < 8; ++c) {
            const float* wr = Wx + c * 8;                     // wave-uniform
#pragma unroll
            for (int i = 0; i < 8; ++i) y[i] = fmaf(x[cur][c], wr[i], y[i]);
        }
#pragma unroll
        for (int i = 0; i < 8; ++i) y[i] = fmaxf(y[i], 0.f);

        if (j == 0) {
            if (ch) {   // layer 5: average with recomputed f1 ll
                float xc[4];
#pragma unroll
                for (int c = 0; c < 4; ++c)
                    xc[c] = ch[(((size_t)b * 4 + c) * NU + u) * NA + a];
                float t[8];
#pragma unroll
                for (int i = 0; i < 8; ++i) t[i] = b1[i];
#pragma unroll
                for (int c = 0; c < 4; ++c)
#pragma unroll
                    for (int i = 0; i < 8; ++i)
                        t[i] = fmaf(xc[c], W1[c * 8 + i], t[i]);
#pragma unroll
                for (int i = 0; i < 8; ++i)
                    y[i] = (y[i] + fmaxf(t[i], 0.f)) * 0.5f;
            }
            store8(ll_out + (base_off + (size_t)u * NA) * 8, y);
        } else if (j == 1) {
            float s[8];
#pragma unroll
            for (int i = 0; i < 8; ++i) s[i] = wave_reduce_sum(y[i]);
            if (lane == 0) {
                float* lp = lg_sum + (b * NU + u) * 8;
#pragma unroll
                for (int i = 0; i < 8; ++i) atomicAdd(lp + i, s[i]);
            }
        } else {
#pragma unroll
            for (int i = 0; i < 8; ++i) acc[i] += y[i];
        }
    }
    if (j == 2) {
        const float invU = 1.f / 16.f;
#pragma unroll
        for (int i = 0; i < 8; ++i) acc[i] *= invU;
        store8(gl_out + ((size_t)b * NA + a) * 8, acc);
    } else if (j == 3) {
#pragma unroll
        for (int i = 0; i < 8; ++i) acc[i] = wave_reduce_sum(acc[i]);
        if (lane == 0) {
            float* gp2 = gg_sum + b * 8;
#pragma unroll
            for (int i = 0; i < 8; ++i) atomicAdd(gp2 + i, acc[i]);
        }
    }
}

// ---------------- Layers 2..7: IN-PLACE fallback (per-u barrier) ----------------
__global__ __launch_bounds__(256, 8) void layer_main_ip(
    const unsigned short* ll_in, const unsigned short* __restrict__ gl_in,
    const unsigned short* __restrict__ gl_skip,
    const float* __restrict__ base, const float* __restrict__ Wl,
    const unsigned short* __restrict__ ll_skip,
    const float* __restrict__ ch, const float* __restrict__ W1,
    const float* __restrict__ b1,
    unsigned short* ll_out, float* __restrict__ lg_sum,
    unsigned short* __restrict__ gl_out, float* __restrict__ gg_sum)
{
    const int b = blockIdx.x;
    const int abase = blockIdx.y * 64;
    const int lane = threadIdx.x & 63;
    const int j = __builtin_amdgcn_readfirstlane((int)(threadIdx.x >> 6));
    const int a = abase + lane;

    float g[8];
    load8(gl_in + ((size_t)b * NA + a) * 8, g);
    if (gl_skip) {
        float s[8];
        load8(gl_skip + ((size_t)b * NA + a) * 8, s);
#pragma unroll
        for (int i = 0; i < 8; ++i) g[i] = (g[i] + s[i]) * 0.5f;
    }
    float cj[8];
#pragma unroll
    for (int i = 0; i < 8; ++i) cj[i] = 0.f;
#pragma unroll
    for (int c = 0; c < 8; ++c) {
        const float* wr = Wl + (j * 32 + 16 + c) * 8;
#pragma unroll
        for (int i = 0; i < 8; ++i) cj[i] = fmaf(g[c], wr[i], cj[i]);
    }

    const float* Wx = Wl + j * 256;
    float acc[8];
#pragma unroll
    for (int i = 0; i < 8; ++i) acc[i] = 0.f;

    for (int u = 0; u < NU; ++u) {
        const size_t xoff = (((size_t)(b * NU + u)) * NA + a) * 8;
        float x[8];
        load8(ll_in + xoff, x);
        float sk[8], xc[4];
        if (j == 0) {
            if (ll_skip) load8(ll_skip + xoff, sk);
            else if (ch) {
#pragma unroll
                for (int c = 0; c < 4; ++c)
                    xc[c] = ch[(((size_t)b * 4 + c) * NU + u) * NA + a];
            }
        }
        __syncthreads();   // all waves read x[u] before j0 overwrites

        const float* bp = base + (b * NU + u) * 32 + j * 8;
        float y[8];
#pragma unroll
        for (int i = 0; i < 8; ++i) y[i] = cj[i] + bp[i];
#pragma unroll
        for (int c = 0; c < 8; ++c) {
            const float* wr = Wx + c * 8;
#pragma unroll
            for (int i = 0; i < 8; ++i) y[i] = fmaf(x[c], wr[i], y[i]);
        }
#pragma unroll
        for (int i = 0; i < 8; ++i) y[i] = fmaxf(y[i], 0.f);

        if (j == 0) {
            if (ll_skip) {
#pragma unroll
                for (int i = 0; i < 8; ++i) y[i] = (y[i] + sk[i]) * 0.5f;
            } else if (ch) {
                float t[8];
#pragma unroll
                for (int i = 0; i < 8; ++i) t[i] = b1[i];
#pragma unroll
                for (int c = 0; c < 4; ++c)
#pragma unroll
                    for (int i = 0; i < 8; ++i)
                        t[i] = fmaf(xc[c], W1[c * 8 + i], t[i]);
#pragma unroll
                for (int i = 0; i < 8; ++i)
                    y[i] = (y[i] + fmaxf(t[i], 0.f)) * 0.5f;
            }
            store8(ll_out + xoff, y);
        } else if (j == 1) {
            float s[8];
#pragma unroll
            for (int i = 0; i < 8; ++i) s[i] = wave_reduce_sum(y[i]);
            if (lane == 0) {
                float* lp = lg_sum + (b * NU + u) * 8;
#pragma unroll
                for (int i = 0; i < 8; ++i) atomicAdd(lp + i, s[i]);
            }
        } else {
#pragma unroll
            for (int i = 0; i < 8; ++i) acc[i] += y[i];
        }
    }
    if (j == 2) {
        const float invU = 1.f / 16.f;
#pragma unroll
        for (int i = 0; i < 8; ++i) acc[i] *= invU;
        store8(gl_out + ((size_t)b * NA + a) * 8, acc);
    } else if (j == 3) {
#pragma unroll
        for (int i = 0; i < 8; ++i) acc[i] = wave_reduce_sum(acc[i]);
        if (lane == 0) {
            float* gp2 = gg_sum + b * 8;
#pragma unroll
            for (int i = 0; i < 8; ++i) atomicAdd(gp2 + i, acc[i]);
        }
    }
}

// ---------------- Layer 8 ----------------
// ll3 != nullptr: ll7 holds RAW f7 ll; combine (ll7+ll3)/2 here.
// ll3 == nullptr: ll7 already has the skip applied.
__global__ __launch_bounds__(256, 4) void layer_out(
    const unsigned short* __restrict__ ll7, const unsigned short* __restrict__ ll3,
    const float* __restrict__ lg7, const float* __restrict__ lg3,   // raw sums
    const unsigned short* __restrict__ gl7, const unsigned short* __restrict__ gl3,
    const float* __restrict__ gg7, const float* __restrict__ gg3,   // raw sums
    const float* __restrict__ W8, const float* __restrict__ b8,
    float* __restrict__ out)
{
    const int b = blockIdx.x;
    const int abase = blockIdx.y * 64;
    const int lane = threadIdx.x & 63;
    const int ug = threadIdx.x >> 6;
    const int a = abase + lane;
    __shared__ float so[4 * 64];

    float acc = 0.f;
#pragma unroll
    for (int uu = 0; uu < 4; ++uu) {
        const int u = ug * 4 + uu;
        const size_t xoff = (((size_t)(b * NU + u)) * NA + a) * 8;
        float x[8];
        load8(ll7 + xoff, x);
        if (ll3) {
            float x3[8];
            load8(ll3 + xoff, x3);
#pragma unroll
            for (int c = 0; c < 8; ++c) x[c] = (x[c] + x3[c]) * 0.5f;
        }
#pragma unroll
        for (int c = 0; c < 8; ++c) acc += x[c] * W8[c];
    }
    so[ug * 64 + lane] = acc;
    __syncthreads();
    if (ug == 0) {
        const float invA = 1.f / 1024.f, invUA = 1.f / 16384.f, invU = 1.f / 16.f;
        float sb = b8[0];
#pragma unroll
        for (int c = 0; c < 8; ++c) {
            float s7 = 0.f, s3 = 0.f;
#pragma unroll
            for (int u = 0; u < NU; ++u) {
                s7 += lg7[(b * NU + u) * 8 + c];
                s3 += lg3[(b * NU + u) * 8 + c];
            }
            sb += ((s7 * invA + s3 * invA) * 0.5f * invU) * W8[8 + c];
        }
#pragma unroll
        for (int c = 0; c < 8; ++c)
            sb += ((gg7[b * 8 + c] + gg3[b * 8 + c]) * invUA * 0.5f) * W8[24 + c];

        float asum = (so[lane] + so[64 + lane] + so[128 + lane] + so[192 + lane]) * invU;
        float g7[8], g3[8];
        load8(gl7 + ((size_t)b * NA + a) * 8, g7);
        load8(gl3 + ((size_t)b * NA + a) * 8, g3);
#pragma unroll
        for (int c = 0; c < 8; ++c)
            asum += 0.5f * (g7[c] + g3[c]) * W8[16 + c];
        out[(size_t)b * NA + a] = (asum + sb) * PI_F;
    }
}

extern "C" void kernel_launch(void* const* d_in, const int* in_sizes, int n_in,
                              void* d_out, int out_size, void* d_ws, size_t ws_size,
                              hipStream_t stream) {
    const float* channel = (const float*)d_in[0];
    const float* W1 = (const float*)d_in[1];
    const float* b1 = (const float*)d_in[2];
    const float* Wm = (const float*)d_in[3];
    const float* bm = (const float*)d_in[4];
    const float* W8 = (const float*)d_in[5];
    const float* b8 = (const float*)d_in[6];

    const size_t LL = (size_t)NB * NU * NA * 8;  // 16,777,216 bf16 elems
    const size_t GL = (size_t)NB * NA * 8;       // 1,048,576
    const size_t LG = (size_t)NB * NU * 8;
    const size_t GG = (size_t)NB * 8;
    const size_t tail_f32 = 7 * LG + 7 * GG + 2048 * 32;

    const size_t need_big = (3 * LL + 4 * GL) * 2 + tail_f32 * 4;
    const bool big = ws_size >= need_big;

    unsigned short* A = (unsigned short*)d_ws;
    unsigned short* Bp = big ? (A + LL) : A;            // fallback: B aliases A
    unsigned short* C = Bp + LL;                        // pinned f3
    unsigned short* glb = C + LL;                       // 4 x GL bf16
    unsigned short* P0 = glb, *P1 = glb + GL, *P2 = glb + 2 * GL, *P3 = glb + 3 * GL;
    float* lgb = (float*)(glb + 4 * GL);                // 7 x LG fp32
    float* ggb = lgb + 7 * LG;                          // 7 x GG fp32
    float* base = ggb + 7 * GG;                         // 2048 x 32 fp32

    hipMemsetAsync(lgb, 0, (7 * LG + 7 * GG) * sizeof(float), stream);

    dim3 grid(NB, NA / 64), blk(256);

    // L1: ch -> A; gl -> P0; lg0, gg0
    layer_first<<<grid, blk, 0, stream>>>(channel, W1, b1, A, lgb, P0, ggb);

    if (big) {
        // L2: A -> B, gl P0 -> P1
        prep_base_k<<<8, 256, 0, stream>>>(lgb, nullptr, ggb, nullptr, Wm, bm, base);
        layer_main_pp<<<grid, blk, 0, stream>>>(A, P0, nullptr, base, Wm,
            nullptr, nullptr, nullptr, Bp, lgb + 1 * LG, P1, ggb + 1 * GG);
        // L3: B -> C (pin f3), gl P1 -> P2 (pin f3 gl)
        prep_base_k<<<8, 256, 0, stream>>>(lgb + 1 * LG, nullptr, ggb + 1 * GG, nullptr,
                                           Wm + 1024, bm + 32, base);
        layer_main_pp<<<grid, blk, 0, stream>>>(Bp, P1, nullptr, base, Wm + 1024,
            nullptr, nullptr, nullptr, C, lgb + 2 * LG, P2, ggb + 2 * GG);
        // L4: C -> A, gl P2 -> P3
        prep_base_k<<<8, 256, 0, stream>>>(lgb + 2 * LG, nullptr, ggb + 2 * GG, nullptr,
                                           Wm + 2048, bm + 64, base);
        layer_main_pp<<<grid, blk, 0, stream>>>(C, P2, nullptr, base, Wm + 2048,
            nullptr, nullptr, nullptr, A, lgb + 3 * LG, P3, ggb + 3 * GG);
        // L5: A -> B (ll-skip: recompute f1 from ch), gl P3 -> P1
        prep_base_k<<<8, 256, 0, stream>>>(lgb + 3 * LG, nullptr, ggb + 3 * GG, nullptr,
                                           Wm + 3072, bm + 96, base);
        layer_main_pp<<<grid, blk, 0, stream>>>(A, P3, nullptr, base, Wm + 3072,
            channel, W1, b1, Bp, lgb + 4 * LG, P1, ggb + 4 * GG);
        // L6: B -> A (input-side skip: lg0/gg0/P0), gl P1 -> P3
        prep_base_k<<<8, 256, 0, stream>>>(lgb + 4 * LG, lgb, ggb + 4 * GG, ggb,
                                           Wm + 4096, bm + 128, base);
        layer_main_pp<<<grid, blk, 0, stream>>>(Bp, P1, P0, base, Wm + 4096,
            nullptr, nullptr, nullptr, A, lgb + 5 * LG, P3, ggb + 5 * GG);
        // L7: A -> B RAW (skip applied in L8), gl P3 -> P1
        prep_base_k<<<8, 256, 0, stream>>>(lgb + 5 * LG, nullptr, ggb + 5 * GG, nullptr,
                                           Wm + 5120, bm + 160, base);
        layer_main_pp<<<grid, blk, 0, stream>>>(A, P3, nullptr, base, Wm + 5120,
            nullptr, nullptr, nullptr, Bp, lgb + 6 * LG, P1, ggb + 6 * GG);
        // L8: combine raw f7 (B) with f3 (C)
        layer_out<<<grid, blk, 0, stream>>>(Bp, C, lgb + 6 * LG, lgb + 2 * LG,
                                            P1, P2, ggb + 6 * GG, ggb + 2 * GG,
                                            W8, b8, (float*)d_out);
    } else {
        // In-place fallback: A only + pinned C.
        prep_base_k<<<8, 256, 0, stream>>>(lgb, nullptr, ggb, nullptr, Wm, bm, base);
        layer_main_ip<<<grid, blk, 0, stream>>>(A, P0, nullptr, base, Wm,
            nullptr, nullptr, nullptr, nullptr, A, lgb + 1 * LG, P1, ggb + 1 * GG);
        prep_base_k<<<8, 256, 0, stream>>>(lgb + 1 * LG, nullptr, ggb + 1 * GG, nullptr,
                                           Wm + 1024, bm + 32, base);
        layer_main_ip<<<grid, blk, 0, stream>>>(A, P1, nullptr, base, Wm + 1024,
            nullptr, nullptr, nullptr, nullptr, C, lgb + 2 * LG, P2, ggb + 2 * GG);
        prep_base_k<<<8, 256, 0, stream>>>(lgb + 2 * LG, nullptr, ggb + 2 * GG, nullptr,
                                           Wm + 2048, bm + 64, base);
        layer_main_ip<<<grid, blk, 0, stream>>>(C, P2, nullptr, base, Wm + 2048,
            nullptr, nullptr, nullptr, nullptr, A, lgb + 3 * LG, P3, ggb + 3 * GG);
        prep_base_k<<<8, 256, 0, stream>>>(lgb + 3 * LG, nullptr, ggb + 3 * GG, nullptr,
                                           Wm + 3072, bm + 96, base);
        layer_main_ip<<<grid, blk, 0, stream>>>(A, P3, nullptr, base, Wm + 3072,
            nullptr, channel, W1, b1, A, lgb + 4 * LG, P1, ggb + 4 * GG);
        prep_base_k<<<8, 256, 0, stream>>>(lgb + 4 * LG, lgb, ggb + 4 * GG, ggb,
                                           Wm + 4096, bm + 128, base);
        layer_main_ip<<<grid, blk, 0, stream>>>(A, P1, P0, base, Wm + 4096,
            nullptr, nullptr, nullptr, nullptr, A, lgb + 5 * LG, P3, ggb + 5 * GG);
        prep_base_k<<<8, 256, 0, stream>>>(lgb + 5 * LG, nullptr, ggb + 5 * GG, nullptr,
                                           Wm + 5120, bm + 160, base);
        layer_main_ip<<<grid, blk, 0, stream>>>(A, P3, nullptr, base, Wm + 5120,
            C, nullptr, nullptr, nullptr, A, lgb + 6 * LG, P1, ggb + 6 * GG);
        layer_out<<<grid, blk, 0, stream>>>(A, nullptr, lgb + 6 * LG, lgb + 2 * LG,
                                            P1, P2, ggb + 6 * GG, ggb + 2 * GG,
                                            W8, b8, (float*)d_out);
    }
}